// Round 5
// baseline (2045.600 us; speedup 1.0000x reference)
//
#include <hip/hip_runtime.h>
#include <math.h>

#define T_ 80
#define B_ 32
#define N_ 2560            // T_*B_
#define LH_ 256

typedef __attribute__((ext_vector_type(8))) short short8;
typedef __attribute__((ext_vector_type(4))) float f32x4;
#define MFMA16(a, b, c) __builtin_amdgcn_mfma_f32_16x16x32_bf16((a), (b), (c), 0, 0, 0)

__device__ __forceinline__ float lrelu(float v) { return v > 0.f ? v : 0.01f * v; }
__device__ __forceinline__ short f2bf(float f) {        // RNE float->bf16 bits
    unsigned u = __float_as_uint(f);
    return (short)((u + 0x7fffu + ((u >> 16) & 1u)) >> 16);
}

// ================= weight pack kernels (fp32 -> bf16, MFMA-friendly) =============
__global__ void pack1_k(const float* __restrict__ w, short* __restrict__ d) {
    int g = blockIdx.x * 256 + threadIdx.x;          // 8*32*32
    int ky = g >> 10, oc = (g >> 5) & 31, k = g & 31, kx = k >> 2, ci = k & 3;
    d[g] = f2bf(w[((oc * 4 + ci) * 8 + ky) * 8 + kx]);
}
__global__ void pack2_k(const float* __restrict__ w, short* __restrict__ d) {
    int g = blockIdx.x * 256 + threadIdx.x;          // 16*64*32
    int t = g >> 11, oc = (g >> 5) & 63, ci = g & 31, ky = t >> 2, kx = t & 3;
    d[g] = f2bf(w[((oc * 32 + ci) * 4 + ky) * 4 + kx]);
}
__global__ void pack3_k(const float* __restrict__ w, short* __restrict__ d) {
    int g = blockIdx.x * 256 + threadIdx.x;          // 18*64*32
    int tkc = g >> 11, oc = (g >> 5) & 63, c32 = g & 31;
    int t = tkc >> 1, kc = tkc & 1, ky = t / 3, kx = t % 3;
    d[g] = f2bf(w[((oc * 64 + kc * 32 + c32) * 3 + ky) * 3 + kx]);
}
__global__ void packfc_k(const float* __restrict__ w, short* __restrict__ d) {
    int g = blockIdx.x * 256 + threadIdx.x;          // 512*3136
    int j = g / 3136, kp = g % 3136, p = kp >> 6, oc = kp & 63;
    d[g] = f2bf(w[j * 3136 + oc * 49 + p]);
}
__global__ void packih_k(const float* __restrict__ w, short* __restrict__ d) {
    int g = blockIdx.x * 256 + threadIdx.x;          // 1024*512
    int r = g >> 9, k = g & 511;
    d[g] = f2bf(w[r * 529 + k]);
}

// ================= conv1 MFMA: x[N,4,84,84] -> h1_cl[N,400,32] bf16 ==============
#define C1_RS 344            // 86 x-slots * 4 ci (entries per row)
__global__ __launch_bounds__(512) void conv1_mfma(
    const float* __restrict__ x, const short* __restrict__ wp1,  // [8][32][32]
    const float* __restrict__ bias, short* __restrict__ h1) {    // [N][400][32]
    __shared__ short xs[44 * C1_RS];      // 30.3 KB
    __shared__ short ob[208 * 32];        // 13.3 KB
    int blk = blockIdx.x, n = blk >> 1, h = blk & 1, tid = threadIdx.x;
    for (int i = tid; i < 44 * 84; i += 512) {   // one float4 (4 x-values) each
        int ry = i / 84, xi4 = i % 84;
        int ci = xi4 / 21, x4 = xi4 % 21;
        int iy = ry + h * 40 - 1;
        if (iy < 0 || iy > 83) continue;
        float4 v = *(const float4*)(x + (size_t)(n * 4 + ci) * 7056 + iy * 84 + x4 * 4);
        int base = ry * C1_RS + (x4 * 4 + 1) * 4 + ci;
        xs[base] = f2bf(v.x); xs[base + 4] = f2bf(v.y);
        xs[base + 8] = f2bf(v.z); xs[base + 12] = f2bf(v.w);
    }
    for (int i = tid; i < 44 * 4; i += 512)      // zero x-slot 0 (x = -1)
        xs[(i >> 2) * C1_RS + (i & 3)] = 0;
    if (h == 0) for (int i = tid; i < C1_RS; i += 512) xs[i] = 0;  // row iy=-1
    __syncthreads();

    int lane = tid & 63, wid = tid >> 6;
    int lr = lane & 15, kq = lane >> 4;
    short8 bfr[8][2];
#pragma unroll
    for (int ky = 0; ky < 8; ++ky)
#pragma unroll
        for (int nt = 0; nt < 2; ++nt)
            bfr[ky][nt] = *(const short8*)&wp1[((ky * 32) + nt * 16 + lr) * 32 + kq * 8];
    float b0 = bias[lr], b1 = bias[16 + lr];

    for (int t = wid; t < 13; t += 8) {
        int p = t * 16 + lr; if (p > 199) p = 199;       // clamp (masked at store)
        int oy = p / 20, ox = p % 20;
        f32x4 acc0 = {0.f, 0.f, 0.f, 0.f}, acc1 = {0.f, 0.f, 0.f, 0.f};
#pragma unroll
        for (int ky = 0; ky < 8; ++ky) {
            int ry = oy * 4 + ky;
            short8 af = *(const short8*)&xs[ry * C1_RS + ox * 16 + kq * 8];
            acc0 = MFMA16(af, bfr[ky][0], acc0);
            acc1 = MFMA16(af, bfr[ky][1], acc1);
        }
        int pm = t * 16 + kq * 4;
#pragma unroll
        for (int r = 0; r < 4; ++r) {
            ob[(pm + r) * 32 + lr]      = f2bf(lrelu(acc0[r] + b0));
            ob[(pm + r) * 32 + 16 + lr] = f2bf(lrelu(acc1[r] + b1));
        }
    }
    __syncthreads();
    uint4* dst = (uint4*)(h1 + (size_t)n * 12800 + h * 6400);
    for (int i = tid; i < 800; i += 512) dst[i] = ((uint4*)ob)[i];
}

// ================= conv2 MFMA: h1_cl -> h2_cl[N,81,64] bf16 ======================
__global__ __launch_bounds__(512) void conv2_mfma(
    const short* __restrict__ h1, const short* __restrict__ wp2,  // [16][64][32]
    const float* __restrict__ bias, short* __restrict__ h2) {
    __shared__ short in_s[400 * 40];      // 32 KB (pix stride padded 32->40)
    __shared__ short ob[96 * 64];         // 12.3 KB
    int n = blockIdx.x, tid = threadIdx.x;
    const uint4* src = (const uint4*)(h1 + (size_t)n * 12800);
    for (int i = tid; i < 1600; i += 512) {
        *(uint4*)&in_s[(i >> 2) * 40 + (i & 3) * 8] = src[i];
    }
    __syncthreads();
    int lane = tid & 63, wid = tid >> 6;
    int nt = wid & 3, mh = wid >> 2;
    int lr = lane & 15, kq = lane >> 4;
    short8 bfr[16];
#pragma unroll
    for (int t = 0; t < 16; ++t)
        bfr[t] = *(const short8*)&wp2[(t * 64 + nt * 16 + lr) * 32 + kq * 8];
    float bl = bias[nt * 16 + lr];
    for (int mt = mh * 3; mt < mh * 3 + 3; ++mt) {
        int p = mt * 16 + lr; if (p > 80) p = 80;
        int oy = p / 9, ox = p % 9;
        f32x4 acc = {0.f, 0.f, 0.f, 0.f};
#pragma unroll
        for (int ky = 0; ky < 4; ++ky)
#pragma unroll
            for (int kx = 0; kx < 4; ++kx) {
                int pix = (oy * 2 + ky) * 20 + ox * 2 + kx;
                short8 af = *(const short8*)&in_s[pix * 40 + kq * 8];
                acc = MFMA16(af, bfr[ky * 4 + kx], acc);
            }
        int pm = mt * 16 + kq * 4;
#pragma unroll
        for (int r = 0; r < 4; ++r)
            ob[(pm + r) * 64 + nt * 16 + lr] = f2bf(lrelu(acc[r] + bl));
    }
    __syncthreads();
    uint4* dst = (uint4*)(h2 + (size_t)n * 5184);
    for (int i = tid; i < 648; i += 512) dst[i] = ((uint4*)ob)[i];
}

// ================= conv3 MFMA: h2_cl -> h3_cl[N,49*64] bf16 ======================
__global__ __launch_bounds__(512) void conv3_mfma(
    const short* __restrict__ h2, const short* __restrict__ wp3,  // [9][2][64][32]
    const float* __restrict__ bias, short* __restrict__ h3) {
    __shared__ short in_s[81 * 72];       // 11.7 KB (pix stride 64->72)
    __shared__ short ob[64 * 64];         // 8 KB
    int n = blockIdx.x, tid = threadIdx.x;
    const uint4* src = (const uint4*)(h2 + (size_t)n * 5184);
    for (int i = tid; i < 648; i += 512) {
        *(uint4*)&in_s[(i >> 3) * 72 + (i & 7) * 8] = src[i];
    }
    __syncthreads();
    int lane = tid & 63, wid = tid >> 6;
    int nt = wid & 3, mh = wid >> 2;
    int lr = lane & 15, kq = lane >> 4;
    short8 bfr[18];
#pragma unroll
    for (int t = 0; t < 18; ++t)
        bfr[t] = *(const short8*)&wp3[(t * 64 + nt * 16 + lr) * 32 + kq * 8];
    float bl = bias[nt * 16 + lr];
    for (int mt = mh * 2; mt < mh * 2 + 2; ++mt) {
        int p = mt * 16 + lr; if (p > 48) p = 48;
        int oy = p / 7, ox = p % 7;
        f32x4 acc = {0.f, 0.f, 0.f, 0.f};
#pragma unroll
        for (int ky = 0; ky < 3; ++ky)
#pragma unroll
            for (int kx = 0; kx < 3; ++kx) {
                int pix = (oy + ky) * 9 + ox + kx;
#pragma unroll
                for (int kc = 0; kc < 2; ++kc) {
                    short8 af = *(const short8*)&in_s[pix * 72 + kc * 32 + kq * 8];
                    acc = MFMA16(af, bfr[(ky * 3 + kx) * 2 + kc], acc);
                }
            }
        int pm = mt * 16 + kq * 4;
#pragma unroll
        for (int r = 0; r < 4; ++r)
            ob[(pm + r) * 64 + nt * 16 + lr] = f2bf(lrelu(acc[r] + bl));
    }
    __syncthreads();
    uint4* dst = (uint4*)(h3 + (size_t)n * 3136);
    for (int i = tid; i < 392; i += 512) dst[i] = ((uint4*)ob)[i];
}

// ========== bf16 GEMM, tile 128x128: C[M,N] = A[M,K] @ B[N,K]^T =================
template <int OUT>
__global__ __launch_bounds__(256) void gemm_bf16(
    const short* __restrict__ A, const short* __restrict__ B,
    const float* __restrict__ bias, void* __restrict__ Cout,
    int M, int N, int K, int ldc) {
    __shared__ short smem[20480];                    // As[2][5120] | Bs[2][5120]
    int m0 = blockIdx.y * 128, n0 = blockIdx.x * 128;
    int tid = threadIdx.x;
    int lane = tid & 63, wid = tid >> 6;
    int wr = wid >> 1, wc = wid & 1;
    int lr = lane & 15, kq = lane >> 4;
    f32x4 acc[4][4];
#pragma unroll
    for (int i = 0; i < 4; ++i)
#pragma unroll
        for (int j = 0; j < 4; ++j) acc[i][j] = (f32x4){0.f, 0.f, 0.f, 0.f};

    int nsteps = K >> 5;
#define STAGE(k0, buf)                                                          \
    {                                                                           \
        short* As = smem + (buf) * 5120;                                        \
        short* Bs = smem + 10240 + (buf) * 5120;                                \
        for (int i = tid; i < 512; i += 256) {                                  \
            int row = i >> 2, c4 = i & 3;                                       \
            *(uint4*)&As[row * 40 + c4 * 8] =                                   \
                *(const uint4*)&A[(size_t)(m0 + row) * K + (k0) + c4 * 8];      \
            *(uint4*)&Bs[row * 40 + c4 * 8] =                                   \
                *(const uint4*)&B[(size_t)(n0 + row) * K + (k0) + c4 * 8];      \
        }                                                                       \
    }
    STAGE(0, 0);
    __syncthreads();
    for (int ks = 0; ks < nsteps; ++ks) {
        int buf = ks & 1;
        if (ks + 1 < nsteps) STAGE((ks + 1) * 32, buf ^ 1);
        short* As = smem + buf * 5120;
        short* Bs = smem + 10240 + buf * 5120;
        short8 af[4], bfr[4];
#pragma unroll
        for (int i = 0; i < 4; ++i)
            af[i] = *(const short8*)&As[(wr * 64 + i * 16 + lr) * 40 + kq * 8];
#pragma unroll
        for (int j = 0; j < 4; ++j)
            bfr[j] = *(const short8*)&Bs[(wc * 64 + j * 16 + lr) * 40 + kq * 8];
#pragma unroll
        for (int i = 0; i < 4; ++i)
#pragma unroll
            for (int j = 0; j < 4; ++j)
                acc[i][j] = MFMA16(af[i], bfr[j], acc[i][j]);
        __syncthreads();
    }
#undef STAGE
    if (OUT == 0) {
        float* C = (float*)Cout;
#pragma unroll
        for (int i = 0; i < 4; ++i)
#pragma unroll
            for (int j = 0; j < 4; ++j)
#pragma unroll
                for (int r = 0; r < 4; ++r) {
                    int row = m0 + wr * 64 + i * 16 + kq * 4 + r;
                    int col = n0 + wc * 64 + j * 16 + lr;
                    C[(size_t)row * ldc + col] = acc[i][j][r];
                }
    } else {
        short* ob = smem;                             // 128x128 bf16 bounce
#pragma unroll
        for (int i = 0; i < 4; ++i)
#pragma unroll
            for (int j = 0; j < 4; ++j) {
                int col = wc * 64 + j * 16 + lr;
                float bl = bias[n0 + col];
#pragma unroll
                for (int r = 0; r < 4; ++r) {
                    int row = wr * 64 + i * 16 + kq * 4 + r;
                    ob[row * 128 + col] = f2bf(lrelu(acc[i][j][r] + bl));
                }
            }
        __syncthreads();
        short* C = (short*)Cout;
        for (int i = tid; i < 2048; i += 256) {
            int row = i >> 4, c16 = i & 15;
            *(uint4*)&C[(size_t)(m0 + row) * ldc + n0 + c16 * 8] =
                *(uint4*)&ob[row * 128 + c16 * 8];
        }
    }
}

// ---------- gates epilogue: + bih + bhh + reward*wih[:,512] + wih[:,513+la] ------
__global__ void gx_epi_k(float* __restrict__ gx, const float* __restrict__ reward,
                         const int* __restrict__ la, const float* __restrict__ wih,
                         const float* __restrict__ bih, const float* __restrict__ bhh) {
    int gid = blockIdx.x * 256 + threadIdx.x;       // N_*1024
    int n = gid >> 10, j = gid & 1023;
    const float* wr = wih + (size_t)j * 529;
    gx[gid] += bih[j] + bhh[j] + reward[n] * wr[512] + wr[513 + la[n]];
}

// ---------- LSTM v4: 1 WG per batch, full Whh resident in the WG's VGPRs --------
// 1024 threads: thread tid owns gate row tid entirely (64 x float4 = 256 VGPRs;
// launch_bounds(1024,1) -> 4 waves/SIMD x 512-VGPR budget holds it).  h lives in
// LDS (written by this WG's own pointwise) -> NO cross-WG sync, no flags, no
// polling.  Matvec LDS reads are all-lane broadcasts (conflict-free).  2
// __syncthreads per step.  VALU-bound: ~0.85us/step/CU, 32 CUs concurrent.
__global__ __launch_bounds__(1024, 1) void lstm1_k(
    const float* __restrict__ gx,        // [N_,1024]
    const float* __restrict__ whh,       // [1024,256]
    const unsigned char* __restrict__ dones,
    const float* __restrict__ hx,        // [2,B_,256]
    float* __restrict__ hs) {            // [N_,256]
    const int b = blockIdx.x, tid = threadIdx.x;
    __shared__ __align__(16) float hh_s[256];
    __shared__ float gate_s[1024];

    // ---- whole Whh row for this thread into VGPRs, once ----
    float4 w[64];
    {
        const float4* wrow = (const float4*)(whh + (size_t)tid * 256);
#pragma unroll
        for (int c = 0; c < 64; ++c) w[c] = wrow[c];
    }

    float cc = 0.f;
    if (tid < 256) {
        hh_s[tid] = hx[b * LH_ + tid];
        cc = hx[(size_t)B_ * LH_ + b * LH_ + tid];
    }
    __syncthreads();

    for (int t = 0; t < T_; ++t) {
        const int nb = t * B_ + b;
        const bool dn = dones[nb] != 0;
        float gxv = gx[(size_t)nb * 1024 + tid];   // issues now, waited on at use
        if (dn && tid < 256) hh_s[tid] = 0.f;      // zero carry-h on done
        __syncthreads();                            // h(t-1) complete before reads

        float a0 = 0.f, a1 = 0.f, a2 = 0.f, a3 = 0.f;
        const float4* h4p = (const float4*)hh_s;
#pragma unroll
        for (int c = 0; c < 64; c += 4) {          // 4 chains for ILP, static idx
            float4 h0 = h4p[c], h1v = h4p[c + 1], h2v = h4p[c + 2], h3v = h4p[c + 3];
            a0 = fmaf(w[c].x, h0.x, a0);       a0 = fmaf(w[c].y, h0.y, a0);
            a0 = fmaf(w[c].z, h0.z, a0);       a0 = fmaf(w[c].w, h0.w, a0);
            a1 = fmaf(w[c + 1].x, h1v.x, a1);  a1 = fmaf(w[c + 1].y, h1v.y, a1);
            a1 = fmaf(w[c + 1].z, h1v.z, a1);  a1 = fmaf(w[c + 1].w, h1v.w, a1);
            a2 = fmaf(w[c + 2].x, h2v.x, a2);  a2 = fmaf(w[c + 2].y, h2v.y, a2);
            a2 = fmaf(w[c + 2].z, h2v.z, a2);  a2 = fmaf(w[c + 2].w, h2v.w, a2);
            a3 = fmaf(w[c + 3].x, h3v.x, a3);  a3 = fmaf(w[c + 3].y, h3v.y, a3);
            a3 = fmaf(w[c + 3].z, h3v.z, a3);  a3 = fmaf(w[c + 3].w, h3v.w, a3);
        }
        gate_s[tid] = ((a0 + a1) + (a2 + a3)) + gxv;
        __syncthreads();                            // gates complete

        if (tid < 256) {
            float gi = gate_s[tid], gf = gate_s[256 + tid];
            float gg = gate_s[512 + tid], go = gate_s[768 + tid];
            float ccv = dn ? 0.f : cc;
            float si = 1.f / (1.f + expf(-gi));
            float sf = 1.f / (1.f + expf(-gf));
            float so = 1.f / (1.f + expf(-go));
            float c2 = sf * ccv + si * tanhf(gg);
            float h2 = so * tanhf(c2);
            cc = c2;
            hh_s[tid] = h2;                         // next step reads after top sync
            hs[(size_t)nb * LH_ + tid] = h2;
        }
    }
}

// ---------- heads ----------
__global__ void head_k(const float* __restrict__ hs,
                       const float* __restrict__ aw, const float* __restrict__ ab,
                       const float* __restrict__ cw, const float* __restrict__ cb,
                       float* __restrict__ out) {
    int gid = blockIdx.x * 256 + threadIdx.x;       // N_*17
    if (gid >= N_ * 17) return;
    int n = gid / 17, r = gid % 17;
    const float* f = hs + (size_t)n * 256;
    if (r < 16) {
        const float* w = aw + r * 256;
        float acc = ab[r];
        for (int k = 0; k < 256; ++k) acc = fmaf(f[k], w[k], acc);
        if (isnan(acc)) acc = 1e-12f;
        out[(size_t)n * 16 + r] = acc;
    } else {
        float acc = cb[0];
        for (int k = 0; k < 256; ++k) acc = fmaf(f[k], cw[k], acc);
        out[(size_t)N_ * 16 + n] = acc;
    }
}

extern "C" void kernel_launch(void* const* d_in, const int* in_sizes, int n_in,
                              void* d_out, int out_size, void* d_ws, size_t ws_size,
                              hipStream_t stream) {
    const float* x      = (const float*)d_in[0];
    const int* la       = (const int*)d_in[1];
    const float* reward = (const float*)d_in[2];
    const unsigned char* dones = (const unsigned char*)d_in[3];
    const float* hx     = (const float*)d_in[4];
    const float* c1w = (const float*)d_in[5];  const float* c1b = (const float*)d_in[6];
    const float* c2w = (const float*)d_in[7];  const float* c2b = (const float*)d_in[8];
    const float* c3w = (const float*)d_in[9];  const float* c3b = (const float*)d_in[10];
    const float* fcw = (const float*)d_in[11]; const float* fcb = (const float*)d_in[12];
    const float* wih = (const float*)d_in[13]; const float* whh = (const float*)d_in[14];
    const float* bih = (const float*)d_in[15]; const float* bhh = (const float*)d_in[16];
    const float* aw  = (const float*)d_in[17]; const float* ab  = (const float*)d_in[18];
    const float* cw  = (const float*)d_in[19]; const float* cb  = (const float*)d_in[20];

    char* wsb = (char*)d_ws;
    short* h1   = (short*)(wsb);                         // 65,536,000 B
    short* h2   = (short*)(wsb + 65536000);              // 26,542,080
    short* h3   = (short*)(wsb + 92078080);              // 16,056,320
    short* hfc  = (short*)(wsb + 108134400);             //  2,621,440
    float* gx   = (float*)(wsb + 110755840);             // 10,485,760
    float* hs   = (float*)(wsb + 121241600);             //  2,621,440
    short* wp1  = (short*)(wsb + 123929600);             //     16,384
    short* wp2  = (short*)(wsb + 123945984);             //     65,536
    short* wp3  = (short*)(wsb + 124011520);             //     73,728
    short* wfcP = (short*)(wsb + 124085248);             //  3,211,264
    short* wihP = (short*)(wsb + 127296512);             //  1,048,576

    pack1_k<<<32, 256, 0, stream>>>(c1w, wp1);
    pack2_k<<<128, 256, 0, stream>>>(c2w, wp2);
    pack3_k<<<144, 256, 0, stream>>>(c3w, wp3);
    packfc_k<<<6272, 256, 0, stream>>>(fcw, wfcP);
    packih_k<<<2048, 256, 0, stream>>>(wih, wihP);

    conv1_mfma<<<5120, 512, 0, stream>>>(x, wp1, c1b, h1);
    conv2_mfma<<<2560, 512, 0, stream>>>(h1, wp2, c2b, h2);
    conv3_mfma<<<2560, 512, 0, stream>>>(h2, wp3, c3b, h3);

    gemm_bf16<1><<<dim3(4, 20), 256, 0, stream>>>(h3, wfcP, fcb, hfc, 2560, 512, 3136, 512);
    gemm_bf16<0><<<dim3(8, 20), 256, 0, stream>>>(hfc, wihP, nullptr, gx, 2560, 1024, 512, 1024);
    gx_epi_k<<<10240, 256, 0, stream>>>(gx, reward, la, wih, bih, bhh);

    lstm1_k<<<32, 1024, 0, stream>>>(gx, whh, dones, hx, hs);
    head_k<<<170, 256, 0, stream>>>(hs, aw, ab, cw, cb, (float*)d_out);
}

// Round 6
// 725.012 us; speedup vs baseline: 2.8215x; 2.8215x over previous
//
#include <hip/hip_runtime.h>
#include <math.h>

#define T_ 80
#define B_ 32
#define N_ 2560            // T_*B_
#define LH_ 256

typedef __attribute__((ext_vector_type(8))) short short8;
typedef __attribute__((ext_vector_type(4))) float f32x4;
#define MFMA16(a, b, c) __builtin_amdgcn_mfma_f32_16x16x32_bf16((a), (b), (c), 0, 0, 0)

__device__ __forceinline__ float lrelu(float v) { return v > 0.f ? v : 0.01f * v; }
__device__ __forceinline__ short f2bf(float f) {        // RNE float->bf16 bits
    unsigned u = __float_as_uint(f);
    return (short)((u + 0x7fffu + ((u >> 16) & 1u)) >> 16);
}

// ================= weight pack kernels (fp32 -> bf16, MFMA-friendly) =============
__global__ void pack1_k(const float* __restrict__ w, short* __restrict__ d) {
    int g = blockIdx.x * 256 + threadIdx.x;          // 8*32*32
    int ky = g >> 10, oc = (g >> 5) & 31, k = g & 31, kx = k >> 2, ci = k & 3;
    d[g] = f2bf(w[((oc * 4 + ci) * 8 + ky) * 8 + kx]);
}
__global__ void pack2_k(const float* __restrict__ w, short* __restrict__ d) {
    int g = blockIdx.x * 256 + threadIdx.x;          // 16*64*32
    int t = g >> 11, oc = (g >> 5) & 63, ci = g & 31, ky = t >> 2, kx = t & 3;
    d[g] = f2bf(w[((oc * 32 + ci) * 4 + ky) * 4 + kx]);
}
__global__ void pack3_k(const float* __restrict__ w, short* __restrict__ d) {
    int g = blockIdx.x * 256 + threadIdx.x;          // 18*64*32
    int tkc = g >> 11, oc = (g >> 5) & 63, c32 = g & 31;
    int t = tkc >> 1, kc = tkc & 1, ky = t / 3, kx = t % 3;
    d[g] = f2bf(w[((oc * 64 + kc * 32 + c32) * 3 + ky) * 3 + kx]);
}
__global__ void packfc_k(const float* __restrict__ w, short* __restrict__ d) {
    int g = blockIdx.x * 256 + threadIdx.x;          // 512*3136
    int j = g / 3136, kp = g % 3136, p = kp >> 6, oc = kp & 63;
    d[g] = f2bf(w[j * 3136 + oc * 49 + p]);
}
__global__ void packih_k(const float* __restrict__ w, short* __restrict__ d) {
    int g = blockIdx.x * 256 + threadIdx.x;          // 1024*512
    int r = g >> 9, k = g & 511;
    d[g] = f2bf(w[r * 529 + k]);
}
__global__ void zero_flags_k(int* __restrict__ flags) { flags[threadIdx.x] = 0; }

// ================= conv1 MFMA: x[N,4,84,84] -> h1_cl[N,400,32] bf16 ==============
#define C1_RS 344            // 86 x-slots * 4 ci (entries per row)
__global__ __launch_bounds__(512) void conv1_mfma(
    const float* __restrict__ x, const short* __restrict__ wp1,  // [8][32][32]
    const float* __restrict__ bias, short* __restrict__ h1) {    // [N][400][32]
    __shared__ short xs[44 * C1_RS];      // 30.3 KB
    __shared__ short ob[208 * 32];        // 13.3 KB
    int blk = blockIdx.x, n = blk >> 1, h = blk & 1, tid = threadIdx.x;
    for (int i = tid; i < 44 * 84; i += 512) {   // one float4 (4 x-values) each
        int ry = i / 84, xi4 = i % 84;
        int ci = xi4 / 21, x4 = xi4 % 21;
        int iy = ry + h * 40 - 1;
        if (iy < 0 || iy > 83) continue;
        float4 v = *(const float4*)(x + (size_t)(n * 4 + ci) * 7056 + iy * 84 + x4 * 4);
        int base = ry * C1_RS + (x4 * 4 + 1) * 4 + ci;
        xs[base] = f2bf(v.x); xs[base + 4] = f2bf(v.y);
        xs[base + 8] = f2bf(v.z); xs[base + 12] = f2bf(v.w);
    }
    for (int i = tid; i < 44 * 4; i += 512)      // zero x-slot 0 (x = -1)
        xs[(i >> 2) * C1_RS + (i & 3)] = 0;
    if (h == 0) for (int i = tid; i < C1_RS; i += 512) xs[i] = 0;  // row iy=-1
    __syncthreads();

    int lane = tid & 63, wid = tid >> 6;
    int lr = lane & 15, kq = lane >> 4;
    short8 bfr[8][2];
#pragma unroll
    for (int ky = 0; ky < 8; ++ky)
#pragma unroll
        for (int nt = 0; nt < 2; ++nt)
            bfr[ky][nt] = *(const short8*)&wp1[((ky * 32) + nt * 16 + lr) * 32 + kq * 8];
    float b0 = bias[lr], b1 = bias[16 + lr];

    for (int t = wid; t < 13; t += 8) {
        int p = t * 16 + lr; if (p > 199) p = 199;       // clamp (masked at store)
        int oy = p / 20, ox = p % 20;
        f32x4 acc0 = {0.f, 0.f, 0.f, 0.f}, acc1 = {0.f, 0.f, 0.f, 0.f};
#pragma unroll
        for (int ky = 0; ky < 8; ++ky) {
            int ry = oy * 4 + ky;
            short8 af = *(const short8*)&xs[ry * C1_RS + ox * 16 + kq * 8];
            acc0 = MFMA16(af, bfr[ky][0], acc0);
            acc1 = MFMA16(af, bfr[ky][1], acc1);
        }
        int pm = t * 16 + kq * 4;
#pragma unroll
        for (int r = 0; r < 4; ++r) {
            ob[(pm + r) * 32 + lr]      = f2bf(lrelu(acc0[r] + b0));
            ob[(pm + r) * 32 + 16 + lr] = f2bf(lrelu(acc1[r] + b1));
        }
    }
    __syncthreads();
    uint4* dst = (uint4*)(h1 + (size_t)n * 12800 + h * 6400);
    for (int i = tid; i < 800; i += 512) dst[i] = ((uint4*)ob)[i];
}

// ================= conv2 MFMA: h1_cl -> h2_cl[N,81,64] bf16 ======================
__global__ __launch_bounds__(512) void conv2_mfma(
    const short* __restrict__ h1, const short* __restrict__ wp2,  // [16][64][32]
    const float* __restrict__ bias, short* __restrict__ h2) {
    __shared__ short in_s[400 * 40];      // 32 KB (pix stride padded 32->40)
    __shared__ short ob[96 * 64];         // 12.3 KB
    int n = blockIdx.x, tid = threadIdx.x;
    const uint4* src = (const uint4*)(h1 + (size_t)n * 12800);
    for (int i = tid; i < 1600; i += 512) {
        *(uint4*)&in_s[(i >> 2) * 40 + (i & 3) * 8] = src[i];
    }
    __syncthreads();
    int lane = tid & 63, wid = tid >> 6;
    int nt = wid & 3, mh = wid >> 2;
    int lr = lane & 15, kq = lane >> 4;
    short8 bfr[16];
#pragma unroll
    for (int t = 0; t < 16; ++t)
        bfr[t] = *(const short8*)&wp2[(t * 64 + nt * 16 + lr) * 32 + kq * 8];
    float bl = bias[nt * 16 + lr];
    for (int mt = mh * 3; mt < mh * 3 + 3; ++mt) {
        int p = mt * 16 + lr; if (p > 80) p = 80;
        int oy = p / 9, ox = p % 9;
        f32x4 acc = {0.f, 0.f, 0.f, 0.f};
#pragma unroll
        for (int ky = 0; ky < 4; ++ky)
#pragma unroll
            for (int kx = 0; kx < 4; ++kx) {
                int pix = (oy * 2 + ky) * 20 + ox * 2 + kx;
                short8 af = *(const short8*)&in_s[pix * 40 + kq * 8];
                acc = MFMA16(af, bfr[ky * 4 + kx], acc);
            }
        int pm = mt * 16 + kq * 4;
#pragma unroll
        for (int r = 0; r < 4; ++r)
            ob[(pm + r) * 64 + nt * 16 + lr] = f2bf(lrelu(acc[r] + bl));
    }
    __syncthreads();
    uint4* dst = (uint4*)(h2 + (size_t)n * 5184);
    for (int i = tid; i < 648; i += 512) dst[i] = ((uint4*)ob)[i];
}

// ================= conv3 MFMA: h2_cl -> h3_cl[N,49*64] bf16 ======================
__global__ __launch_bounds__(512) void conv3_mfma(
    const short* __restrict__ h2, const short* __restrict__ wp3,  // [9][2][64][32]
    const float* __restrict__ bias, short* __restrict__ h3) {
    __shared__ short in_s[81 * 72];       // 11.7 KB (pix stride 64->72)
    __shared__ short ob[64 * 64];         // 8 KB
    int n = blockIdx.x, tid = threadIdx.x;
    const uint4* src = (const uint4*)(h2 + (size_t)n * 5184);
    for (int i = tid; i < 648; i += 512) {
        *(uint4*)&in_s[(i >> 3) * 72 + (i & 7) * 8] = src[i];
    }
    __syncthreads();
    int lane = tid & 63, wid = tid >> 6;
    int nt = wid & 3, mh = wid >> 2;
    int lr = lane & 15, kq = lane >> 4;
    short8 bfr[18];
#pragma unroll
    for (int t = 0; t < 18; ++t)
        bfr[t] = *(const short8*)&wp3[(t * 64 + nt * 16 + lr) * 32 + kq * 8];
    float bl = bias[nt * 16 + lr];
    for (int mt = mh * 2; mt < mh * 2 + 2; ++mt) {
        int p = mt * 16 + lr; if (p > 48) p = 48;
        int oy = p / 7, ox = p % 7;
        f32x4 acc = {0.f, 0.f, 0.f, 0.f};
#pragma unroll
        for (int ky = 0; ky < 3; ++ky)
#pragma unroll
            for (int kx = 0; kx < 3; ++kx) {
                int pix = (oy + ky) * 9 + ox + kx;
#pragma unroll
                for (int kc = 0; kc < 2; ++kc) {
                    short8 af = *(const short8*)&in_s[pix * 72 + kc * 32 + kq * 8];
                    acc = MFMA16(af, bfr[(ky * 3 + kx) * 2 + kc], acc);
                }
            }
        int pm = mt * 16 + kq * 4;
#pragma unroll
        for (int r = 0; r < 4; ++r)
            ob[(pm + r) * 64 + nt * 16 + lr] = f2bf(lrelu(acc[r] + bl));
    }
    __syncthreads();
    uint4* dst = (uint4*)(h3 + (size_t)n * 3136);
    for (int i = tid; i < 392; i += 512) dst[i] = ((uint4*)ob)[i];
}

// ========== bf16 GEMM, tile 128x128: C[M,N] = A[M,K] @ B[N,K]^T =================
template <int OUT>
__global__ __launch_bounds__(256) void gemm_bf16(
    const short* __restrict__ A, const short* __restrict__ B,
    const float* __restrict__ bias, void* __restrict__ Cout,
    int M, int N, int K, int ldc) {
    __shared__ short smem[20480];                    // As[2][5120] | Bs[2][5120]
    int m0 = blockIdx.y * 128, n0 = blockIdx.x * 128;
    int tid = threadIdx.x;
    int lane = tid & 63, wid = tid >> 6;
    int wr = wid >> 1, wc = wid & 1;
    int lr = lane & 15, kq = lane >> 4;
    f32x4 acc[4][4];
#pragma unroll
    for (int i = 0; i < 4; ++i)
#pragma unroll
        for (int j = 0; j < 4; ++j) acc[i][j] = (f32x4){0.f, 0.f, 0.f, 0.f};

    int nsteps = K >> 5;
#define STAGE(k0, buf)                                                          \
    {                                                                           \
        short* As = smem + (buf) * 5120;                                        \
        short* Bs = smem + 10240 + (buf) * 5120;                                \
        for (int i = tid; i < 512; i += 256) {                                  \
            int row = i >> 2, c4 = i & 3;                                       \
            *(uint4*)&As[row * 40 + c4 * 8] =                                   \
                *(const uint4*)&A[(size_t)(m0 + row) * K + (k0) + c4 * 8];      \
            *(uint4*)&Bs[row * 40 + c4 * 8] =                                   \
                *(const uint4*)&B[(size_t)(n0 + row) * K + (k0) + c4 * 8];      \
        }                                                                       \
    }
    STAGE(0, 0);
    __syncthreads();
    for (int ks = 0; ks < nsteps; ++ks) {
        int buf = ks & 1;
        if (ks + 1 < nsteps) STAGE((ks + 1) * 32, buf ^ 1);
        short* As = smem + buf * 5120;
        short* Bs = smem + 10240 + buf * 5120;
        short8 af[4], bfr[4];
#pragma unroll
        for (int i = 0; i < 4; ++i)
            af[i] = *(const short8*)&As[(wr * 64 + i * 16 + lr) * 40 + kq * 8];
#pragma unroll
        for (int j = 0; j < 4; ++j)
            bfr[j] = *(const short8*)&Bs[(wc * 64 + j * 16 + lr) * 40 + kq * 8];
#pragma unroll
        for (int i = 0; i < 4; ++i)
#pragma unroll
            for (int j = 0; j < 4; ++j)
                acc[i][j] = MFMA16(af[i], bfr[j], acc[i][j]);
        __syncthreads();
    }
#undef STAGE
    if (OUT == 0) {
        float* C = (float*)Cout;
#pragma unroll
        for (int i = 0; i < 4; ++i)
#pragma unroll
            for (int j = 0; j < 4; ++j)
#pragma unroll
                for (int r = 0; r < 4; ++r) {
                    int row = m0 + wr * 64 + i * 16 + kq * 4 + r;
                    int col = n0 + wc * 64 + j * 16 + lr;
                    C[(size_t)row * ldc + col] = acc[i][j][r];
                }
    } else {
        short* ob = smem;                             // 128x128 bf16 bounce
#pragma unroll
        for (int i = 0; i < 4; ++i)
#pragma unroll
            for (int j = 0; j < 4; ++j) {
                int col = wc * 64 + j * 16 + lr;
                float bl = bias[n0 + col];
#pragma unroll
                for (int r = 0; r < 4; ++r) {
                    int row = wr * 64 + i * 16 + kq * 4 + r;
                    ob[row * 128 + col] = f2bf(lrelu(acc[i][j][r] + bl));
                }
            }
        __syncthreads();
        short* C = (short*)Cout;
        for (int i = tid; i < 2048; i += 256) {
            int row = i >> 4, c16 = i & 15;
            *(uint4*)&C[(size_t)(m0 + row) * ldc + n0 + c16 * 8] =
                *(uint4*)&ob[row * 128 + c16 * 8];
        }
    }
}

// ---------- gates epilogue: + bih + bhh + reward*wih[:,512] + wih[:,513+la] ------
__global__ void gx_epi_k(float* __restrict__ gx, const float* __restrict__ reward,
                         const int* __restrict__ la, const float* __restrict__ wih,
                         const float* __restrict__ bih, const float* __restrict__ bhh) {
    int gid = blockIdx.x * 256 + threadIdx.x;       // N_*1024
    int n = gid >> 10, j = gid & 1023;
    const float* wr = wih + (size_t)j * 529;
    gx[gid] += bih[j] + bhh[j] + reward[n] * wr[512] + wr[513 + la[n]];
}

// ---------- LSTM v6: XCD-local sync. 64 WGs = 8 batch-groups x 8 hidden-slices ---
// DECODE SWAP vs R3: grp = blk&7, s = blk>>3  ->  the 8 slice-WGs of group grp sit
// at blk = grp, grp+8, ..., grp+56, i.e. blk%8 == grp == SAME XCD (round-robin
// dispatch).  All handshake traffic (counter + hbuf) stays in that XCD's L2.
// One release-ordered counter per group (128B apart): after step t it reads 8*t.
__global__ __launch_bounds__(512) void lstm64_k(
    const float* __restrict__ gx,        // [N_,1024]
    const float* __restrict__ whh,       // [1024,256]
    const unsigned char* __restrict__ dones,
    const float* __restrict__ hx,        // [2,B_,256]
    float* __restrict__ hs,              // [N_,256]
    float* __restrict__ hbuf,            // [2][B_][256] ping-pong h exchange
    int* __restrict__ cnt) {             // [8 groups x 32-int stride]
    const int tid = threadIdx.x;
    const int grp = blockIdx.x & 7;      // batch group (== XCD id)
    const int s   = blockIdx.x >> 3;     // hidden slice 0..7
    const int r = tid >> 2;              // gate row 0..127 within slice
    const int q = tid & 3;               // k-quarter
    const int g = r >> 5, jr = r & 31;
    const int grow = g * 256 + s * 32 + jr;  // global gate row

    __shared__ __align__(16) float h_swz[4 * 256];   // [bi][c][q][e] swizzled
    __shared__ float gate_s[4][128];

    // ---- load Whh slice into registers (L1/L2-resident at worst) ----
    float4 wreg[16];
    {
        const float4* wrow = (const float4*)(whh + (size_t)grow * 256 + q * 64);
#pragma unroll
        for (int c = 0; c < 16; ++c) wreg[c] = wrow[c];
    }
#pragma unroll
    for (int c = 0; c < 16; ++c)
        asm volatile("" : "+v"(wreg[c].x), "+v"(wreg[c].y),
                          "+v"(wreg[c].z), "+v"(wreg[c].w));

    // ---- carry c: tid<128 owns (bi=tid>>5, unit jj=tid&31) ----
    float cc = 0.f;
    if (tid < 128) {
        int bi = tid >> 5, jj = tid & 31;
        cc = hx[(size_t)B_ * LH_ + (grp * 4 + bi) * LH_ + s * 32 + jj];
    }

    for (int t = 1; t <= T_; ++t) {
        // ---- preload gx (independent of h) before the sync wait ----
        float gxv[4];
        if (q == 0) {
#pragma unroll
            for (int bi = 0; bi < 4; ++bi) {
                int nb = (t - 1) * B_ + grp * 4 + bi;
                gxv[bi] = gx[(size_t)nb * 1024 + grow];
            }
        }
        // ---- wait: all 8 slice-WGs of this group done with step t-1 ----
        if (t > 1) {
            if (tid == 0) {
                while (__hip_atomic_load(&cnt[grp * 32], __ATOMIC_ACQUIRE,
                                         __HIP_MEMORY_SCOPE_AGENT) < 8 * (t - 1))
                    __builtin_amdgcn_s_sleep(1);
            }
            __syncthreads();
        }
        // ---- stage h for 4 batches into swizzled LDS ----
#pragma unroll
        for (int l = 0; l < 2; ++l) {
            int idx = tid + l * 512;                 // 0..1023
            int bi = idx >> 8, j = idx & 255;
            int b = grp * 4 + bi;
            int nb = (t - 1) * B_ + b;
            float hv;
            if (t == 1) hv = hx[b * LH_ + j];
            else        hv = __hip_atomic_load(&hbuf[((t - 1) & 1) * B_ * LH_ + b * LH_ + j],
                                               __ATOMIC_RELAXED, __HIP_MEMORY_SCOPE_AGENT);
            if (dones[nb]) hv = 0.f;
            int qq = j >> 6, ccc = (j >> 2) & 15, ee = j & 3;
            h_swz[bi * 256 + ccc * 16 + qq * 4 + ee] = hv;
        }
        __syncthreads();

        // ---- matvec: 128 rows x 4 batches, 4 threads/row over k ----
        float acc[4] = {0.f, 0.f, 0.f, 0.f};
#pragma unroll
        for (int c = 0; c < 16; ++c) {
            float4 w4 = wreg[c];
#pragma unroll
            for (int bi = 0; bi < 4; ++bi) {
                float4 h4 = *(const float4*)&h_swz[bi * 256 + c * 16 + q * 4];
                acc[bi] = fmaf(w4.x, h4.x, acc[bi]);
                acc[bi] = fmaf(w4.y, h4.y, acc[bi]);
                acc[bi] = fmaf(w4.z, h4.z, acc[bi]);
                acc[bi] = fmaf(w4.w, h4.w, acc[bi]);
            }
        }
#pragma unroll
        for (int bi = 0; bi < 4; ++bi) {
            acc[bi] += __shfl_xor(acc[bi], 1);
            acc[bi] += __shfl_xor(acc[bi], 2);
        }
        if (q == 0) {
#pragma unroll
            for (int bi = 0; bi < 4; ++bi)
                gate_s[bi][r] = acc[bi] + gxv[bi];
        }
        __syncthreads();

        // ---- pointwise cell + publish (tid<128: 4 batches x 32 units) ----
        if (tid < 128) {
            int bi = tid >> 5, jj = tid & 31;
            int b = grp * 4 + bi;
            int nb = (t - 1) * B_ + b;
            float gi = gate_s[bi][jj],      gf = gate_s[bi][32 + jj];
            float gg = gate_s[bi][64 + jj], go = gate_s[bi][96 + jj];
            float ccv = dones[nb] ? 0.f : cc;
            float si = 1.f / (1.f + expf(-gi));
            float sf = 1.f / (1.f + expf(-gf));
            float so = 1.f / (1.f + expf(-go));
            float c2 = sf * ccv + si * tanhf(gg);
            float h2 = so * tanhf(c2);
            cc = c2;
            int hidx = s * 32 + jj;
            hs[(size_t)nb * LH_ + hidx] = h2;
            __hip_atomic_store(&hbuf[(t & 1) * B_ * LH_ + b * LH_ + hidx], h2,
                               __ATOMIC_RELAXED, __HIP_MEMORY_SCOPE_AGENT);
        }
        __syncthreads();   // drains all waves' h stores before the publish
        if (tid == 0)
            __hip_atomic_fetch_add(&cnt[grp * 32], 1, __ATOMIC_RELEASE,
                                   __HIP_MEMORY_SCOPE_AGENT);
    }
}

// ---------- heads ----------
__global__ void head_k(const float* __restrict__ hs,
                       const float* __restrict__ aw, const float* __restrict__ ab,
                       const float* __restrict__ cw, const float* __restrict__ cb,
                       float* __restrict__ out) {
    int gid = blockIdx.x * 256 + threadIdx.x;       // N_*17
    if (gid >= N_ * 17) return;
    int n = gid / 17, r = gid % 17;
    const float* f = hs + (size_t)n * 256;
    if (r < 16) {
        const float* w = aw + r * 256;
        float acc = ab[r];
        for (int k = 0; k < 256; ++k) acc = fmaf(f[k], w[k], acc);
        if (isnan(acc)) acc = 1e-12f;
        out[(size_t)n * 16 + r] = acc;
    } else {
        float acc = cb[0];
        for (int k = 0; k < 256; ++k) acc = fmaf(f[k], cw[k], acc);
        out[(size_t)N_ * 16 + n] = acc;
    }
}

extern "C" void kernel_launch(void* const* d_in, const int* in_sizes, int n_in,
                              void* d_out, int out_size, void* d_ws, size_t ws_size,
                              hipStream_t stream) {
    const float* x      = (const float*)d_in[0];
    const int* la       = (const int*)d_in[1];
    const float* reward = (const float*)d_in[2];
    const unsigned char* dones = (const unsigned char*)d_in[3];
    const float* hx     = (const float*)d_in[4];
    const float* c1w = (const float*)d_in[5];  const float* c1b = (const float*)d_in[6];
    const float* c2w = (const float*)d_in[7];  const float* c2b = (const float*)d_in[8];
    const float* c3w = (const float*)d_in[9];  const float* c3b = (const float*)d_in[10];
    const float* fcw = (const float*)d_in[11]; const float* fcb = (const float*)d_in[12];
    const float* wih = (const float*)d_in[13]; const float* whh = (const float*)d_in[14];
    const float* bih = (const float*)d_in[15]; const float* bhh = (const float*)d_in[16];
    const float* aw  = (const float*)d_in[17]; const float* ab  = (const float*)d_in[18];
    const float* cw  = (const float*)d_in[19]; const float* cb  = (const float*)d_in[20];

    char* wsb = (char*)d_ws;
    short* h1   = (short*)(wsb);                         // 65,536,000 B
    short* h2   = (short*)(wsb + 65536000);              // 26,542,080
    short* h3   = (short*)(wsb + 92078080);              // 16,056,320
    short* hfc  = (short*)(wsb + 108134400);             //  2,621,440
    float* gx   = (float*)(wsb + 110755840);             // 10,485,760
    float* hs   = (float*)(wsb + 121241600);             //  2,621,440
    float* hbuf = (float*)(wsb + 123863040);             //     65,536
    int*   cnt  = (int*)  (wsb + 123928576);             //      1,024 (8 ctr x 128B)
    short* wp1  = (short*)(wsb + 123929600);             //     16,384
    short* wp2  = (short*)(wsb + 123945984);             //     65,536
    short* wp3  = (short*)(wsb + 124011520);             //     73,728
    short* wfcP = (short*)(wsb + 124085248);             //  3,211,264
    short* wihP = (short*)(wsb + 127296512);             //  1,048,576

    pack1_k<<<32, 256, 0, stream>>>(c1w, wp1);
    pack2_k<<<128, 256, 0, stream>>>(c2w, wp2);
    pack3_k<<<144, 256, 0, stream>>>(c3w, wp3);
    packfc_k<<<6272, 256, 0, stream>>>(fcw, wfcP);
    packih_k<<<2048, 256, 0, stream>>>(wih, wihP);
    zero_flags_k<<<1, 256, 0, stream>>>(cnt);

    conv1_mfma<<<5120, 512, 0, stream>>>(x, wp1, c1b, h1);
    conv2_mfma<<<2560, 512, 0, stream>>>(h1, wp2, c2b, h2);
    conv3_mfma<<<2560, 512, 0, stream>>>(h2, wp3, c3b, h3);

    gemm_bf16<1><<<dim3(4, 20), 256, 0, stream>>>(h3, wfcP, fcb, hfc, 2560, 512, 3136, 512);
    gemm_bf16<0><<<dim3(8, 20), 256, 0, stream>>>(hfc, wihP, nullptr, gx, 2560, 1024, 512, 1024);
    gx_epi_k<<<10240, 256, 0, stream>>>(gx, reward, la, wih, bih, bhh);

    lstm64_k<<<64, 512, 0, stream>>>(gx, whh, dones, hx, hs, hbuf, cnt);
    head_k<<<170, 256, 0, stream>>>(hs, aw, ab, cw, cb, (float*)d_out);
}

// Round 7
// 570.119 us; speedup vs baseline: 3.5880x; 1.2717x over previous
//
#include <hip/hip_runtime.h>
#include <math.h>

#define T_ 80
#define B_ 32
#define N_ 2560            // T_*B_
#define LH_ 256

typedef __attribute__((ext_vector_type(8))) short short8;
typedef __attribute__((ext_vector_type(4))) float f32x4;
#define MFMA16(a, b, c) __builtin_amdgcn_mfma_f32_16x16x32_bf16((a), (b), (c), 0, 0, 0)

__device__ __forceinline__ float lrelu(float v) { return v > 0.f ? v : 0.01f * v; }
__device__ __forceinline__ short f2bf(float f) {        // RNE float->bf16 bits
    unsigned u = __float_as_uint(f);
    return (short)((u + 0x7fffu + ((u >> 16) & 1u)) >> 16);
}

// ================= weight pack kernels (fp32 -> bf16, MFMA-friendly) =============
__global__ void pack1_k(const float* __restrict__ w, short* __restrict__ d) {
    int g = blockIdx.x * 256 + threadIdx.x;          // 8*32*32
    int ky = g >> 10, oc = (g >> 5) & 31, k = g & 31, kx = k >> 2, ci = k & 3;
    d[g] = f2bf(w[((oc * 4 + ci) * 8 + ky) * 8 + kx]);
}
__global__ void pack2_k(const float* __restrict__ w, short* __restrict__ d) {
    int g = blockIdx.x * 256 + threadIdx.x;          // 16*64*32
    int t = g >> 11, oc = (g >> 5) & 63, ci = g & 31, ky = t >> 2, kx = t & 3;
    d[g] = f2bf(w[((oc * 32 + ci) * 4 + ky) * 4 + kx]);
}
__global__ void pack3_k(const float* __restrict__ w, short* __restrict__ d) {
    int g = blockIdx.x * 256 + threadIdx.x;          // 18*64*32
    int tkc = g >> 11, oc = (g >> 5) & 63, c32 = g & 31;
    int t = tkc >> 1, kc = tkc & 1, ky = t / 3, kx = t % 3;
    d[g] = f2bf(w[((oc * 64 + kc * 32 + c32) * 3 + ky) * 3 + kx]);
}
__global__ void packfc_k(const float* __restrict__ w, short* __restrict__ d) {
    int g = blockIdx.x * 256 + threadIdx.x;          // 512*3136
    int j = g / 3136, kp = g % 3136, p = kp >> 6, oc = kp & 63;
    d[g] = f2bf(w[j * 3136 + oc * 49 + p]);
}
__global__ void packih_k(const float* __restrict__ w, short* __restrict__ d) {
    int g = blockIdx.x * 256 + threadIdx.x;          // 1024*512
    int r = g >> 9, k = g & 511;
    d[g] = f2bf(w[r * 529 + k]);
}
__global__ void zero_flags_k(int* __restrict__ flags) { flags[threadIdx.x] = 0; }

// ================= conv1 MFMA: x[N,4,84,84] -> h1_cl[N,400,32] bf16 ==============
#define C1_RS 344            // 86 x-slots * 4 ci (entries per row)
__global__ __launch_bounds__(512) void conv1_mfma(
    const float* __restrict__ x, const short* __restrict__ wp1,  // [8][32][32]
    const float* __restrict__ bias, short* __restrict__ h1) {    // [N][400][32]
    __shared__ short xs[44 * C1_RS];      // 30.3 KB
    __shared__ short ob[208 * 32];        // 13.3 KB
    int blk = blockIdx.x, n = blk >> 1, h = blk & 1, tid = threadIdx.x;
    for (int i = tid; i < 44 * 84; i += 512) {   // one float4 (4 x-values) each
        int ry = i / 84, xi4 = i % 84;
        int ci = xi4 / 21, x4 = xi4 % 21;
        int iy = ry + h * 40 - 1;
        if (iy < 0 || iy > 83) continue;
        float4 v = *(const float4*)(x + (size_t)(n * 4 + ci) * 7056 + iy * 84 + x4 * 4);
        int base = ry * C1_RS + (x4 * 4 + 1) * 4 + ci;
        xs[base] = f2bf(v.x); xs[base + 4] = f2bf(v.y);
        xs[base + 8] = f2bf(v.z); xs[base + 12] = f2bf(v.w);
    }
    for (int i = tid; i < 44 * 4; i += 512)      // zero x-slot 0 (x = -1)
        xs[(i >> 2) * C1_RS + (i & 3)] = 0;
    if (h == 0) for (int i = tid; i < C1_RS; i += 512) xs[i] = 0;  // row iy=-1
    __syncthreads();

    int lane = tid & 63, wid = tid >> 6;
    int lr = lane & 15, kq = lane >> 4;
    short8 bfr[8][2];
#pragma unroll
    for (int ky = 0; ky < 8; ++ky)
#pragma unroll
        for (int nt = 0; nt < 2; ++nt)
            bfr[ky][nt] = *(const short8*)&wp1[((ky * 32) + nt * 16 + lr) * 32 + kq * 8];
    float b0 = bias[lr], b1 = bias[16 + lr];

    for (int t = wid; t < 13; t += 8) {
        int p = t * 16 + lr; if (p > 199) p = 199;       // clamp (masked at store)
        int oy = p / 20, ox = p % 20;
        f32x4 acc0 = {0.f, 0.f, 0.f, 0.f}, acc1 = {0.f, 0.f, 0.f, 0.f};
#pragma unroll
        for (int ky = 0; ky < 8; ++ky) {
            int ry = oy * 4 + ky;
            short8 af = *(const short8*)&xs[ry * C1_RS + ox * 16 + kq * 8];
            acc0 = MFMA16(af, bfr[ky][0], acc0);
            acc1 = MFMA16(af, bfr[ky][1], acc1);
        }
        int pm = t * 16 + kq * 4;
#pragma unroll
        for (int r = 0; r < 4; ++r) {
            ob[(pm + r) * 32 + lr]      = f2bf(lrelu(acc0[r] + b0));
            ob[(pm + r) * 32 + 16 + lr] = f2bf(lrelu(acc1[r] + b1));
        }
    }
    __syncthreads();
    uint4* dst = (uint4*)(h1 + (size_t)n * 12800 + h * 6400);
    for (int i = tid; i < 800; i += 512) dst[i] = ((uint4*)ob)[i];
}

// ================= conv2 MFMA: h1_cl -> h2_cl[N,81,64] bf16 ======================
__global__ __launch_bounds__(512) void conv2_mfma(
    const short* __restrict__ h1, const short* __restrict__ wp2,  // [16][64][32]
    const float* __restrict__ bias, short* __restrict__ h2) {
    __shared__ short in_s[400 * 40];      // 32 KB (pix stride padded 32->40)
    __shared__ short ob[96 * 64];         // 12.3 KB
    int n = blockIdx.x, tid = threadIdx.x;
    const uint4* src = (const uint4*)(h1 + (size_t)n * 12800);
    for (int i = tid; i < 1600; i += 512) {
        *(uint4*)&in_s[(i >> 2) * 40 + (i & 3) * 8] = src[i];
    }
    __syncthreads();
    int lane = tid & 63, wid = tid >> 6;
    int nt = wid & 3, mh = wid >> 2;
    int lr = lane & 15, kq = lane >> 4;
    short8 bfr[16];
#pragma unroll
    for (int t = 0; t < 16; ++t)
        bfr[t] = *(const short8*)&wp2[(t * 64 + nt * 16 + lr) * 32 + kq * 8];
    float bl = bias[nt * 16 + lr];
    for (int mt = mh * 3; mt < mh * 3 + 3; ++mt) {
        int p = mt * 16 + lr; if (p > 80) p = 80;
        int oy = p / 9, ox = p % 9;
        f32x4 acc = {0.f, 0.f, 0.f, 0.f};
#pragma unroll
        for (int ky = 0; ky < 4; ++ky)
#pragma unroll
            for (int kx = 0; kx < 4; ++kx) {
                int pix = (oy * 2 + ky) * 20 + ox * 2 + kx;
                short8 af = *(const short8*)&in_s[pix * 40 + kq * 8];
                acc = MFMA16(af, bfr[ky * 4 + kx], acc);
            }
        int pm = mt * 16 + kq * 4;
#pragma unroll
        for (int r = 0; r < 4; ++r)
            ob[(pm + r) * 64 + nt * 16 + lr] = f2bf(lrelu(acc[r] + bl));
    }
    __syncthreads();
    uint4* dst = (uint4*)(h2 + (size_t)n * 5184);
    for (int i = tid; i < 648; i += 512) dst[i] = ((uint4*)ob)[i];
}

// ================= conv3 MFMA: h2_cl -> h3_cl[N,49*64] bf16 ======================
__global__ __launch_bounds__(512) void conv3_mfma(
    const short* __restrict__ h2, const short* __restrict__ wp3,  // [9][2][64][32]
    const float* __restrict__ bias, short* __restrict__ h3) {
    __shared__ short in_s[81 * 72];       // 11.7 KB (pix stride 64->72)
    __shared__ short ob[64 * 64];         // 8 KB
    int n = blockIdx.x, tid = threadIdx.x;
    const uint4* src = (const uint4*)(h2 + (size_t)n * 5184);
    for (int i = tid; i < 648; i += 512) {
        *(uint4*)&in_s[(i >> 3) * 72 + (i & 7) * 8] = src[i];
    }
    __syncthreads();
    int lane = tid & 63, wid = tid >> 6;
    int nt = wid & 3, mh = wid >> 2;
    int lr = lane & 15, kq = lane >> 4;
    short8 bfr[18];
#pragma unroll
    for (int t = 0; t < 18; ++t)
        bfr[t] = *(const short8*)&wp3[(t * 64 + nt * 16 + lr) * 32 + kq * 8];
    float bl = bias[nt * 16 + lr];
    for (int mt = mh * 2; mt < mh * 2 + 2; ++mt) {
        int p = mt * 16 + lr; if (p > 48) p = 48;
        int oy = p / 7, ox = p % 7;
        f32x4 acc = {0.f, 0.f, 0.f, 0.f};
#pragma unroll
        for (int ky = 0; ky < 3; ++ky)
#pragma unroll
            for (int kx = 0; kx < 3; ++kx) {
                int pix = (oy + ky) * 9 + ox + kx;
#pragma unroll
                for (int kc = 0; kc < 2; ++kc) {
                    short8 af = *(const short8*)&in_s[pix * 72 + kc * 32 + kq * 8];
                    acc = MFMA16(af, bfr[(ky * 3 + kx) * 2 + kc], acc);
                }
            }
        int pm = mt * 16 + kq * 4;
#pragma unroll
        for (int r = 0; r < 4; ++r)
            ob[(pm + r) * 64 + nt * 16 + lr] = f2bf(lrelu(acc[r] + bl));
    }
    __syncthreads();
    uint4* dst = (uint4*)(h3 + (size_t)n * 3136);
    for (int i = tid; i < 392; i += 512) dst[i] = ((uint4*)ob)[i];
}

// ========== bf16 GEMM, tile 128x128: C[M,N] = A[M,K] @ B[N,K]^T =================
template <int OUT>
__global__ __launch_bounds__(256) void gemm_bf16(
    const short* __restrict__ A, const short* __restrict__ B,
    const float* __restrict__ bias, void* __restrict__ Cout,
    int M, int N, int K, int ldc) {
    __shared__ short smem[20480];                    // As[2][5120] | Bs[2][5120]
    int m0 = blockIdx.y * 128, n0 = blockIdx.x * 128;
    int tid = threadIdx.x;
    int lane = tid & 63, wid = tid >> 6;
    int wr = wid >> 1, wc = wid & 1;
    int lr = lane & 15, kq = lane >> 4;
    f32x4 acc[4][4];
#pragma unroll
    for (int i = 0; i < 4; ++i)
#pragma unroll
        for (int j = 0; j < 4; ++j) acc[i][j] = (f32x4){0.f, 0.f, 0.f, 0.f};

    int nsteps = K >> 5;
#define STAGE(k0, buf)                                                          \
    {                                                                           \
        short* As = smem + (buf) * 5120;                                        \
        short* Bs = smem + 10240 + (buf) * 5120;                                \
        for (int i = tid; i < 512; i += 256) {                                  \
            int row = i >> 2, c4 = i & 3;                                       \
            *(uint4*)&As[row * 40 + c4 * 8] =                                   \
                *(const uint4*)&A[(size_t)(m0 + row) * K + (k0) + c4 * 8];      \
            *(uint4*)&Bs[row * 40 + c4 * 8] =                                   \
                *(const uint4*)&B[(size_t)(n0 + row) * K + (k0) + c4 * 8];      \
        }                                                                       \
    }
    STAGE(0, 0);
    __syncthreads();
    for (int ks = 0; ks < nsteps; ++ks) {
        int buf = ks & 1;
        if (ks + 1 < nsteps) STAGE((ks + 1) * 32, buf ^ 1);
        short* As = smem + buf * 5120;
        short* Bs = smem + 10240 + buf * 5120;
        short8 af[4], bfr[4];
#pragma unroll
        for (int i = 0; i < 4; ++i)
            af[i] = *(const short8*)&As[(wr * 64 + i * 16 + lr) * 40 + kq * 8];
#pragma unroll
        for (int j = 0; j < 4; ++j)
            bfr[j] = *(const short8*)&Bs[(wc * 64 + j * 16 + lr) * 40 + kq * 8];
#pragma unroll
        for (int i = 0; i < 4; ++i)
#pragma unroll
            for (int j = 0; j < 4; ++j)
                acc[i][j] = MFMA16(af[i], bfr[j], acc[i][j]);
        __syncthreads();
    }
#undef STAGE
    if (OUT == 0) {
        float* C = (float*)Cout;
#pragma unroll
        for (int i = 0; i < 4; ++i)
#pragma unroll
            for (int j = 0; j < 4; ++j)
#pragma unroll
                for (int r = 0; r < 4; ++r) {
                    int row = m0 + wr * 64 + i * 16 + kq * 4 + r;
                    int col = n0 + wc * 64 + j * 16 + lr;
                    C[(size_t)row * ldc + col] = acc[i][j][r];
                }
    } else {
        short* ob = smem;                             // 128x128 bf16 bounce
#pragma unroll
        for (int i = 0; i < 4; ++i)
#pragma unroll
            for (int j = 0; j < 4; ++j) {
                int col = wc * 64 + j * 16 + lr;
                float bl = bias[n0 + col];
#pragma unroll
                for (int r = 0; r < 4; ++r) {
                    int row = wr * 64 + i * 16 + kq * 4 + r;
                    ob[row * 128 + col] = f2bf(lrelu(acc[i][j][r] + bl));
                }
            }
        __syncthreads();
        short* C = (short*)Cout;
        for (int i = tid; i < 2048; i += 256) {
            int row = i >> 4, c16 = i & 15;
            *(uint4*)&C[(size_t)(m0 + row) * ldc + n0 + c16 * 8] =
                *(uint4*)&ob[row * 128 + c16 * 8];
        }
    }
}

// ---------- gates epilogue: + bih + bhh + reward*wih[:,512] + wih[:,513+la] ------
__global__ void gx_epi_k(float* __restrict__ gx, const float* __restrict__ reward,
                         const int* __restrict__ la, const float* __restrict__ wih,
                         const float* __restrict__ bih, const float* __restrict__ bhh) {
    int gid = blockIdx.x * 256 + threadIdx.x;       // N_*1024
    int n = gid >> 10, j = gid & 1023;
    const float* wr = wih + (size_t)j * 529;
    gx[gid] += bih[j] + bhh[j] + reward[n] * wr[512] + wr[513 + la[n]];
}

// ---------- LSTM v7: MFMA recurrence, 16 WGs = 8 batch-groups x 2 hidden-halves --
// blk = half*8 + grp  ->  blk%8 == grp: both halves of a group on the SAME XCD.
// 512 thr = 8 waves; wave w: gate-type gt=w>>1, sub s2=w&1 -> rows gt*256 +
// half*128 + s2*64 .. +63.  Whh rows live in VGPRs as MFMA A-frags afr[4][8]
// (128 VGPR, loaded once, pinned).  Per step: h staged as bf16 B-frags in LDS
// (8 ds_read_b128 + 32 MFMA per wave -- replaces R6's 512 LDS insts/CU), WG-local
// pointwise for 128 units x 4 batches, single-peer exchange of 512 floats.
__global__ __launch_bounds__(512) void lstm16_k(
    const float* __restrict__ gx,        // [N_,1024]
    const float* __restrict__ whh,       // [1024,256] fp32
    const unsigned char* __restrict__ dones,
    const float* __restrict__ hx,        // [2,B_,256]
    float* __restrict__ hs,              // [N_,256]
    float* __restrict__ hpub,            // [2][B_][256] ping-pong h exchange
    int* __restrict__ cnt) {             // [(grp*2+half)*32]
    const int tid = threadIdx.x;
    const int grp  = blockIdx.x & 7;     // batch group (== XCD), batches grp*4..+3
    const int half = blockIdx.x >> 3;    // hidden half: units half*128..+127
    const int lane = tid & 63, w = tid >> 6;
    const int gt = w >> 1, s2 = w & 1;
    const int lr = lane & 15, kq = lane >> 4;

    __shared__ short hB[16 * 264];       // [batch 16][k 256 +8 pad] bf16
    __shared__ float gate_s[4][128][4];  // [gate][unit][batch]

    // ---- resident A-frags: afr[mi][kt], row = gt*256+half*128+s2*64+mi*16+lr ----
    short8 afr[4][8];
#pragma unroll
    for (int mi = 0; mi < 4; ++mi) {
        int row = gt * 256 + half * 128 + s2 * 64 + mi * 16 + lr;
        const float* wr = whh + (size_t)row * 256;
#pragma unroll
        for (int kt = 0; kt < 8; ++kt) {
            int k0 = kt * 32 + kq * 8;
            float4 a = *(const float4*)(wr + k0);
            float4 b = *(const float4*)(wr + k0 + 4);
            short8 f;
            f[0] = f2bf(a.x); f[1] = f2bf(a.y); f[2] = f2bf(a.z); f[3] = f2bf(a.w);
            f[4] = f2bf(b.x); f[5] = f2bf(b.y); f[6] = f2bf(b.z); f[7] = f2bf(b.w);
            afr[mi][kt] = f;
        }
    }
    {   // pin against rematerialization (R2/R3 lesson)
        int* ap = (int*)afr;
#pragma unroll
        for (int i = 0; i < 128; ++i) asm volatile("" : "+v"(ap[i]));
    }

    // zero unused B rows 4..15 once
    for (int i = tid; i < 12 * 264; i += 512) hB[4 * 264 + i] = 0;

    const int u = tid >> 2, bt = tid & 3;        // pointwise ownership
    const int b = grp * 4 + bt, gu = half * 128 + u;
    float cc = hx[(size_t)B_ * LH_ + b * LH_ + gu];
    __syncthreads();

    const int mycnt = (grp * 2 + half) * 32, peercnt = (grp * 2 + (half ^ 1)) * 32;

    for (int t = 1; t <= T_; ++t) {
        const int nb0 = (t - 1) * B_;
        // ---- prefetch gx for pointwise (independent of h) ----
        float gxv[4];
#pragma unroll
        for (int g2 = 0; g2 < 4; ++g2)
            gxv[g2] = gx[(size_t)(nb0 + b) * 1024 + g2 * 256 + gu];

        // ---- wait: peer finished step t-1 ----
        if (t > 1) {
            if (tid == 0) {
                while (__hip_atomic_load(&cnt[peercnt], __ATOMIC_ACQUIRE,
                                         __HIP_MEMORY_SCOPE_AGENT) < t - 1)
                    __builtin_amdgcn_s_sleep(1);
            }
            __syncthreads();
        }
        // ---- stage h(t-1) -> bf16 hB[batch][k] (done-masked) ----
#pragma unroll
        for (int l = 0; l < 2; ++l) {
            int e = tid + l * 512;                   // 0..1023
            int bt2 = e >> 8, k = e & 255;
            int b2 = grp * 4 + bt2;
            float hv = (t == 1) ? hx[b2 * LH_ + k]
                                : hpub[((t - 1) & 1) * 8192 + b2 * 256 + k];
            if (dones[nb0 + b2]) hv = 0.f;
            hB[bt2 * 264 + k] = f2bf(hv);
        }
        __syncthreads();

        // ---- MFMA: G[64 rows][16 cols(4 used)] per wave ----
        f32x4 acc[4] = {{0.f,0.f,0.f,0.f},{0.f,0.f,0.f,0.f},
                        {0.f,0.f,0.f,0.f},{0.f,0.f,0.f,0.f}};
#pragma unroll
        for (int kt = 0; kt < 8; ++kt) {
            short8 bfr = *(const short8*)&hB[lr * 264 + kt * 32 + kq * 8];
#pragma unroll
            for (int mi = 0; mi < 4; ++mi)
                acc[mi] = MFMA16(afr[mi][kt], bfr, acc[mi]);
        }
        if (lr < 4) {                                // cols 0..3 = real batches
#pragma unroll
            for (int mi = 0; mi < 4; ++mi)
#pragma unroll
                for (int r = 0; r < 4; ++r)
                    gate_s[gt][s2 * 64 + mi * 16 + kq * 4 + r][lr] = acc[mi][r];
        }
        __syncthreads();

        // ---- pointwise: 128 units x 4 batches == 512 threads ----
        {
            bool dn = dones[nb0 + b] != 0;
            float gi = gate_s[0][u][bt] + gxv[0];
            float gf = gate_s[1][u][bt] + gxv[1];
            float gg = gate_s[2][u][bt] + gxv[2];
            float go = gate_s[3][u][bt] + gxv[3];
            float ccv = dn ? 0.f : cc;
            float si = 1.f / (1.f + expf(-gi));
            float sf = 1.f / (1.f + expf(-gf));
            float so = 1.f / (1.f + expf(-go));
            float c2 = sf * ccv + si * tanhf(gg);
            float h2 = so * tanhf(c2);
            cc = c2;
            hs[(size_t)(nb0 + b) * LH_ + gu] = h2;
            __hip_atomic_store(&hpub[(t & 1) * 8192 + b * 256 + gu], h2,
                               __ATOMIC_RELAXED, __HIP_MEMORY_SCOPE_AGENT);
        }
        __syncthreads();   // all waves' hpub stores drained before publish
        if (tid == 0)
            __hip_atomic_store(&cnt[mycnt], t, __ATOMIC_RELEASE,
                               __HIP_MEMORY_SCOPE_AGENT);
    }
}

// ---------- heads ----------
__global__ void head_k(const float* __restrict__ hs,
                       const float* __restrict__ aw, const float* __restrict__ ab,
                       const float* __restrict__ cw, const float* __restrict__ cb,
                       float* __restrict__ out) {
    int gid = blockIdx.x * 256 + threadIdx.x;       // N_*17
    if (gid >= N_ * 17) return;
    int n = gid / 17, r = gid % 17;
    const float* f = hs + (size_t)n * 256;
    if (r < 16) {
        const float* w = aw + r * 256;
        float acc = ab[r];
        for (int k = 0; k < 256; ++k) acc = fmaf(f[k], w[k], acc);
        if (isnan(acc)) acc = 1e-12f;
        out[(size_t)n * 16 + r] = acc;
    } else {
        float acc = cb[0];
        for (int k = 0; k < 256; ++k) acc = fmaf(f[k], cw[k], acc);
        out[(size_t)N_ * 16 + n] = acc;
    }
}

extern "C" void kernel_launch(void* const* d_in, const int* in_sizes, int n_in,
                              void* d_out, int out_size, void* d_ws, size_t ws_size,
                              hipStream_t stream) {
    const float* x      = (const float*)d_in[0];
    const int* la       = (const int*)d_in[1];
    const float* reward = (const float*)d_in[2];
    const unsigned char* dones = (const unsigned char*)d_in[3];
    const float* hx     = (const float*)d_in[4];
    const float* c1w = (const float*)d_in[5];  const float* c1b = (const float*)d_in[6];
    const float* c2w = (const float*)d_in[7];  const float* c2b = (const float*)d_in[8];
    const float* c3w = (const float*)d_in[9];  const float* c3b = (const float*)d_in[10];
    const float* fcw = (const float*)d_in[11]; const float* fcb = (const float*)d_in[12];
    const float* wih = (const float*)d_in[13]; const float* whh = (const float*)d_in[14];
    const float* bih = (const float*)d_in[15]; const float* bhh = (const float*)d_in[16];
    const float* aw  = (const float*)d_in[17]; const float* ab  = (const float*)d_in[18];
    const float* cw  = (const float*)d_in[19]; const float* cb  = (const float*)d_in[20];

    char* wsb = (char*)d_ws;
    short* h1   = (short*)(wsb);                         // 65,536,000 B
    short* h2   = (short*)(wsb + 65536000);              // 26,542,080
    short* h3   = (short*)(wsb + 92078080);              // 16,056,320
    short* hfc  = (short*)(wsb + 108134400);             //  2,621,440
    float* gx   = (float*)(wsb + 110755840);             // 10,485,760
    float* hs   = (float*)(wsb + 121241600);             //  2,621,440
    float* hpub = (float*)(wsb + 123863040);             //     65,536
    int*   cnt  = (int*)  (wsb + 123928576);             //      2,048 (16 ctr x 128B)
    short* wp1  = (short*)(wsb + 123932672);             //     16,384
    short* wp2  = (short*)(wsb + 123949056);             //     65,536
    short* wp3  = (short*)(wsb + 124014592);             //     73,728
    short* wfcP = (short*)(wsb + 124088320);             //  3,211,264
    short* wihP = (short*)(wsb + 127299584);             //  1,048,576

    pack1_k<<<32, 256, 0, stream>>>(c1w, wp1);
    pack2_k<<<128, 256, 0, stream>>>(c2w, wp2);
    pack3_k<<<144, 256, 0, stream>>>(c3w, wp3);
    packfc_k<<<6272, 256, 0, stream>>>(fcw, wfcP);
    packih_k<<<2048, 256, 0, stream>>>(wih, wihP);
    zero_flags_k<<<1, 512, 0, stream>>>(cnt);

    conv1_mfma<<<5120, 512, 0, stream>>>(x, wp1, c1b, h1);
    conv2_mfma<<<2560, 512, 0, stream>>>(h1, wp2, c2b, h2);
    conv3_mfma<<<2560, 512, 0, stream>>>(h2, wp3, c3b, h3);

    gemm_bf16<1><<<dim3(4, 20), 256, 0, stream>>>(h3, wfcP, fcb, hfc, 2560, 512, 3136, 512);
    gemm_bf16<0><<<dim3(8, 20), 256, 0, stream>>>(hfc, wihP, nullptr, gx, 2560, 1024, 512, 1024);
    gx_epi_k<<<10240, 256, 0, stream>>>(gx, reward, la, wih, bih, bhh);

    lstm16_k<<<16, 512, 0, stream>>>(gx, whh, dones, hx, hs, hpub, cnt);
    head_k<<<170, 256, 0, stream>>>(hs, aw, ab, cw, cb, (float*)d_out);
}